// Round 13
// baseline (298.320 us; speedup 1.0000x reference)
//
#include <hip/hip_runtime.h>
#include <math.h>

#define N_NODES 50000
#define N_EDGES 800000
#define ETOT    (N_EDGES + N_NODES)
#define DH      128
#define NH      4
#define LN_EPS  1e-5f
#define NBLK    ((N_NODES + 255) / 256)   // 196 scan blocks
#define LOG2E   1.4426950408889634f

typedef __attribute__((ext_vector_type(8))) short short8;
typedef __attribute__((ext_vector_type(4))) float f32x4;
typedef __attribute__((ext_vector_type(4))) unsigned uint4v;

// ---------- fp32 -> bf16 (RNE) helpers ----------
__device__ __forceinline__ unsigned short f2bf(float f) {
    unsigned u = __float_as_uint(f);
    u += 0x7FFFu + ((u >> 16) & 1u);
    return (unsigned short)(u >> 16);
}
__device__ __forceinline__ float bf2f(unsigned short h) {
    return __uint_as_float(((unsigned)h) << 16);
}
// packed split: two fp32 -> one u32 of 2 bf16 (hi) + residual u32 (lo)
__device__ __forceinline__ void split_pair(float a, float b, unsigned& hi, unsigned& lo) {
    unsigned h;
    asm("v_cvt_pk_bf16_f32 %0, %1, %2" : "=v"(h) : "v"(a), "v"(b));
    const float ra = a - __uint_as_float(h << 16);
    const float rb = b - __uint_as_float(h & 0xffff0000u);
    unsigned l;
    asm("v_cvt_pk_bf16_f32 %0, %1, %2" : "=v"(l) : "v"(ra), "v"(rb));
    hi = h; lo = l;
}

// ---------- fast exact-GELU (A&S 7.1.26 erf, max err ~1.5e-7) ----------
__device__ __forceinline__ float gelu_exact(float x) {
    const float z  = x * 0.70710678118654752f;
    const float az = fabsf(z);
    const float tt = __builtin_amdgcn_rcpf(fmaf(0.3275911f, az, 1.f));
    float p = fmaf(1.061405429f, tt, -1.453152027f);
    p = fmaf(p, tt, 1.421413741f);
    p = fmaf(p, tt, -0.284496736f);
    p = fmaf(p, tt, 0.254829592f);
    p = p * tt;
    const float ez = exp2f(-(z * z) * LOG2E);
    float er = fmaf(-p, ez, 1.f);
    er = copysignf(er, z);
    return x * fmaf(0.5f, er, 0.5f);
}

// ========== pack 5 weight matrices into MFMA B-fragment order (hi/lo) ==========
__global__ __launch_bounds__(256) void pack_w_kernel(
    const float* __restrict__ W0, const float* __restrict__ W1,
    const float* __restrict__ W2, const float* __restrict__ W3,
    const float* __restrict__ W4,
    short* __restrict__ hi, short* __restrict__ lo)
{
    const int idx = blockIdx.x * 256 + threadIdx.x;   // 0..81919
    const int mat = idx >> 14;
    const int rem = idx & 16383;
    const int t = rem >> 12, c = (rem >> 9) & 7, l = (rem >> 3) & 63, j = rem & 7;
    const int k = t * 32 + (l >> 4) * 8 + j;
    const int n = c * 16 + (l & 15);
    const float* W = (mat == 0) ? W0 : (mat == 1) ? W1 : (mat == 2) ? W2
                   : (mat == 3) ? W3 : W4;
    const float v = W[k * DH + n];
    const unsigned short h = f2bf(v);
    hi[idx] = (short)h;
    lo[idx] = (short)f2bf(v - bf2f(h));
}

// ========== split-bf16 MFMA GEMM; fp32 A (in-kernel split), bf16 outputs ==========
#define MTILE 128
__global__ __launch_bounds__(256) void gemm_mfma_kernel(
    const float* __restrict__ A, int m_rows,
    const short* __restrict__ WhiL, const short* __restrict__ WloL,
    const float* __restrict__ biasL, unsigned short* __restrict__ YL,
    const short* __restrict__ WhiR, const short* __restrict__ WloR,
    const float* __restrict__ biasR, unsigned short* __restrict__ YR)
{
    const int w    = threadIdx.x >> 6;
    const int lane = threadIdx.x & 63;
    const short* Whi  = blockIdx.y ? WhiR  : WhiL;
    const short* Wlo  = blockIdx.y ? WloR  : WloL;
    const float* bias = blockIdx.y ? biasR : biasL;
    unsigned short* Y = blockIdx.y ? YR    : YL;

    const int rows0 = blockIdx.x * MTILE + w * 32;
    const int g  = lane >> 4;
    const int rl = lane & 15;

    f32x4 acc[2][8];
    #pragma unroll
    for (int r = 0; r < 2; ++r)
        #pragma unroll
        for (int c = 0; c < 8; ++c)
            acc[r][c] = (f32x4){0.f, 0.f, 0.f, 0.f};

    for (int t = 0; t < 4; ++t) {
        short8 ahi[2], alo[2];
        #pragma unroll
        for (int r = 0; r < 2; ++r) {
            int arow = rows0 + 16 * r + rl;
            arow = (arow < m_rows) ? arow : (m_rows - 1);
            const float* ap = A + (size_t)arow * DH + t * 32 + g * 8;
            const float4 f0 = *(const float4*)ap;
            const float4 f1 = *(const float4*)(ap + 4);
            unsigned h0, l0, h1, l1, h2, l2, h3, l3;
            split_pair(f0.x, f0.y, h0, l0);
            split_pair(f0.z, f0.w, h1, l1);
            split_pair(f1.x, f1.y, h2, l2);
            split_pair(f1.z, f1.w, h3, l3);
            ahi[r] = __builtin_bit_cast(short8, (uint4v){h0, h1, h2, h3});
            alo[r] = __builtin_bit_cast(short8, (uint4v){l0, l1, l2, l3});
        }
        #pragma unroll
        for (int c = 0; c < 8; ++c) {
            const int fidx = ((t * 8 + c) * 64 + lane) * 8;
            const short8 bhi = *(const short8*)(Whi + fidx);
            const short8 blo = *(const short8*)(Wlo + fidx);
            acc[0][c] = __builtin_amdgcn_mfma_f32_16x16x32_bf16(ahi[0], bhi, acc[0][c], 0, 0, 0);
            acc[1][c] = __builtin_amdgcn_mfma_f32_16x16x32_bf16(ahi[1], bhi, acc[1][c], 0, 0, 0);
            acc[0][c] = __builtin_amdgcn_mfma_f32_16x16x32_bf16(alo[0], bhi, acc[0][c], 0, 0, 0);
            acc[1][c] = __builtin_amdgcn_mfma_f32_16x16x32_bf16(alo[1], bhi, acc[1][c], 0, 0, 0);
            acc[0][c] = __builtin_amdgcn_mfma_f32_16x16x32_bf16(ahi[0], blo, acc[0][c], 0, 0, 0);
            acc[1][c] = __builtin_amdgcn_mfma_f32_16x16x32_bf16(ahi[1], blo, acc[1][c], 0, 0, 0);
        }
    }
    #pragma unroll
    for (int c = 0; c < 8; ++c) {
        const int col = c * 16 + rl;
        const float bb = bias[col];
        #pragma unroll
        for (int r = 0; r < 2; ++r) {
            #pragma unroll
            for (int q = 0; q < 4; ++q) {
                const int row = rows0 + 16 * r + g * 4 + q;
                if (row < m_rows)
                    Y[(size_t)row * DH + col] = f2bf(acc[r][c][q] + bb);
            }
        }
    }
}

// ========== gemm1 + fused final LayerNorm: out = LN(A@W + b; g, bt) ==========
__global__ __launch_bounds__(256) void gemm1_ln_kernel(
    const float* __restrict__ A, int m_rows,
    const short* __restrict__ Whi, const short* __restrict__ Wlo,
    const float* __restrict__ bias,
    const float* __restrict__ gam, const float* __restrict__ bet,
    float* __restrict__ out)
{
    const int w    = threadIdx.x >> 6;
    const int lane = threadIdx.x & 63;
    const int rows0 = blockIdx.x * MTILE + w * 32;
    const int g  = lane >> 4;
    const int rl = lane & 15;

    f32x4 acc[2][8];
    #pragma unroll
    for (int r = 0; r < 2; ++r)
        #pragma unroll
        for (int c = 0; c < 8; ++c)
            acc[r][c] = (f32x4){0.f, 0.f, 0.f, 0.f};

    for (int t = 0; t < 4; ++t) {
        short8 ahi[2], alo[2];
        #pragma unroll
        for (int r = 0; r < 2; ++r) {
            int arow = rows0 + 16 * r + rl;
            arow = (arow < m_rows) ? arow : (m_rows - 1);
            const float* ap = A + (size_t)arow * DH + t * 32 + g * 8;
            const float4 f0 = *(const float4*)ap;
            const float4 f1 = *(const float4*)(ap + 4);
            unsigned h0, l0, h1, l1, h2, l2, h3, l3;
            split_pair(f0.x, f0.y, h0, l0);
            split_pair(f0.z, f0.w, h1, l1);
            split_pair(f1.x, f1.y, h2, l2);
            split_pair(f1.z, f1.w, h3, l3);
            ahi[r] = __builtin_bit_cast(short8, (uint4v){h0, h1, h2, h3});
            alo[r] = __builtin_bit_cast(short8, (uint4v){l0, l1, l2, l3});
        }
        #pragma unroll
        for (int c = 0; c < 8; ++c) {
            const int fidx = ((t * 8 + c) * 64 + lane) * 8;
            const short8 bh = *(const short8*)(Whi + fidx);
            const short8 bl = *(const short8*)(Wlo + fidx);
            acc[0][c] = __builtin_amdgcn_mfma_f32_16x16x32_bf16(ahi[0], bh, acc[0][c], 0, 0, 0);
            acc[1][c] = __builtin_amdgcn_mfma_f32_16x16x32_bf16(ahi[1], bh, acc[1][c], 0, 0, 0);
            acc[0][c] = __builtin_amdgcn_mfma_f32_16x16x32_bf16(alo[0], bh, acc[0][c], 0, 0, 0);
            acc[1][c] = __builtin_amdgcn_mfma_f32_16x16x32_bf16(alo[1], bh, acc[1][c], 0, 0, 0);
            acc[0][c] = __builtin_amdgcn_mfma_f32_16x16x32_bf16(ahi[0], bl, acc[0][c], 0, 0, 0);
            acc[1][c] = __builtin_amdgcn_mfma_f32_16x16x32_bf16(ahi[1], bl, acc[1][c], 0, 0, 0);
        }
    }

    float bb[8], gg[8], bt8[8];
    #pragma unroll
    for (int c = 0; c < 8; ++c) {
        const int col = c * 16 + rl;
        bb[c] = bias[col];  gg[c] = gam[col];  bt8[c] = bet[col];
    }
    #pragma unroll
    for (int r = 0; r < 2; ++r) {
        #pragma unroll
        for (int q = 0; q < 4; ++q) {
            float v[8];
            float s = 0.f, sq = 0.f;
            #pragma unroll
            for (int c = 0; c < 8; ++c) {
                v[c] = acc[r][c][q] + bb[c];
                s  += v[c];
                sq  = fmaf(v[c], v[c], sq);
            }
            #pragma unroll
            for (int off = 1; off < 16; off <<= 1) {
                s  += __shfl_xor(s,  off);
                sq += __shfl_xor(sq, off);
            }
            const float mu   = s * (1.f / 128.f);
            const float var  = sq * (1.f / 128.f) - mu * mu;
            const float rstd = rsqrtf(var + LN_EPS);
            const int row = rows0 + 16 * r + g * 4 + q;
            if (row < m_rows) {
                #pragma unroll
                for (int c = 0; c < 8; ++c)
                    out[(size_t)row * DH + c * 16 + rl] =
                        (v[c] - mu) * rstd * gg[c] + bt8[c];
            }
        }
    }
}

// ========================= CSR construction (4-edge ILP) =========================
__global__ __launch_bounds__(256) void degree_kernel(
    const int* __restrict__ eidx, int* __restrict__ deg)
{
    const int base = (blockIdx.x * 256 + threadIdx.x) * 4;
    if (base < N_EDGES) {
        const int4 dv = *(const int4*)(eidx + N_EDGES + base);
        atomicAdd(&deg[dv.x], 1);
        atomicAdd(&deg[dv.y], 1);
        atomicAdd(&deg[dv.z], 1);
        atomicAdd(&deg[dv.w], 1);
    } else if (base < ETOT) {
        const int d0 = base - N_EDGES;
        atomicAdd(&deg[d0], 1);
        atomicAdd(&deg[d0 + 1], 1);
        atomicAdd(&deg[d0 + 2], 1);
        atomicAdd(&deg[d0 + 3], 1);
    }
}

__global__ __launch_bounds__(256) void block_sum_kernel(
    const int* __restrict__ deg, int* __restrict__ bsum)
{
    const int i    = blockIdx.x * 256 + threadIdx.x;
    const int lane = threadIdx.x & 63;
    const int wid  = threadIdx.x >> 6;
    int v = (i < N_NODES) ? deg[i] : 0;
    #pragma unroll
    for (int off = 32; off; off >>= 1) v += __shfl_xor(v, off);
    __shared__ int ws[4];
    if (lane == 0) ws[wid] = v;
    __syncthreads();
    if (threadIdx.x == 0) bsum[blockIdx.x] = ws[0] + ws[1] + ws[2] + ws[3];
}

__global__ __launch_bounds__(256) void scan_partials_kernel(
    const int* __restrict__ bsum, int* __restrict__ boff)
{
    const int t    = threadIdx.x;
    const int lane = t & 63;
    const int wid  = t >> 6;
    int v = (t < NBLK) ? bsum[t] : 0;
    int inc = v;
    #pragma unroll
    for (int off = 1; off < 64; off <<= 1) {
        int u = __shfl_up(inc, off);
        if (lane >= off) inc += u;
    }
    __shared__ int ws[4];
    if (lane == 63) ws[wid] = inc;
    __syncthreads();
    int add = 0;
    for (int w = 0; w < wid; ++w) add += ws[w];
    if (t < NBLK) boff[t] = add + inc - v;
}

__global__ __launch_bounds__(256) void rowptr_kernel(
    const int* __restrict__ deg, const int* __restrict__ boff,
    int* __restrict__ rowptr, int* __restrict__ cursor)
{
    const int i    = blockIdx.x * 256 + threadIdx.x;
    const int lane = threadIdx.x & 63;
    const int wid  = threadIdx.x >> 6;
    int v = (i < N_NODES) ? deg[i] : 0;
    int inc = v;
    #pragma unroll
    for (int off = 1; off < 64; off <<= 1) {
        int u = __shfl_up(inc, off);
        if (lane >= off) inc += u;
    }
    __shared__ int ws[4];
    if (lane == 63) ws[wid] = inc;
    __syncthreads();
    int add = boff[blockIdx.x];
    for (int w = 0; w < wid; ++w) add += ws[w];
    if (i < N_NODES) {
        const int ex = add + inc - v;
        rowptr[i] = ex;
        cursor[i] = ex;
    }
}

__global__ __launch_bounds__(256) void scatter_kernel(
    const int* __restrict__ eidx, int* __restrict__ cursor,
    unsigned short* __restrict__ csr_src)
{
    const int base = (blockIdx.x * 256 + threadIdx.x) * 4;
    if (base < N_EDGES) {
        const int4 sv = *(const int4*)(eidx + base);
        const int4 dv = *(const int4*)(eidx + N_EDGES + base);
        const int t0 = atomicAdd(&cursor[dv.x], 1);
        const int t1 = atomicAdd(&cursor[dv.y], 1);
        const int t2 = atomicAdd(&cursor[dv.z], 1);
        const int t3 = atomicAdd(&cursor[dv.w], 1);
        csr_src[t0] = (unsigned short)sv.x;
        csr_src[t1] = (unsigned short)sv.y;
        csr_src[t2] = (unsigned short)sv.z;
        csr_src[t3] = (unsigned short)sv.w;
    } else if (base < ETOT) {
        const int d0 = base - N_EDGES;
        const int t0 = atomicAdd(&cursor[d0], 1);
        const int t1 = atomicAdd(&cursor[d0 + 1], 1);
        const int t2 = atomicAdd(&cursor[d0 + 2], 1);
        const int t3 = atomicAdd(&cursor[d0 + 3], 1);
        csr_src[t0] = (unsigned short)d0;
        csr_src[t1] = (unsigned short)(d0 + 1);
        csr_src[t2] = (unsigned short)(d0 + 2);
        csr_src[t3] = (unsigned short)(d0 + 3);
    }
}

// ====== fused per-node GAT: register ids + depth-3 gather pipeline ======
// wave = one dst node; 16 lanes/edge (8 bf16 ch/lane), 4 edge slots
__global__ __launch_bounds__(256) void gat_node_kernel(
    const int* __restrict__ rowptr, const int* __restrict__ deg,
    const unsigned short* __restrict__ csr_src,
    const unsigned short* __restrict__ xlb, const unsigned short* __restrict__ xrb,
    const float* __restrict__ att, const float* __restrict__ bias,
    const float* __restrict__ gam, const float* __restrict__ bet,
    float* __restrict__ out)
{
    const int n    = blockIdx.x * 4 + (threadIdx.x >> 6);
    const int lane = threadIdx.x & 63;
    if (n >= N_NODES) return;
    const int q  = lane >> 4;       // edge slot 0..3
    const int r  = lane & 15;       // channel group
    const int c0 = r * 8;

    // xr row (bf16) -> 8 fp32
    const uint4v urw = *(const uint4v*)(xrb + ((size_t)n << 7) + c0);
    float xrv[8];
    #pragma unroll
    for (int k = 0; k < 4; ++k) {
        xrv[2 * k]     = __uint_as_float(urw[k] << 16);
        xrv[2 * k + 1] = __uint_as_float(urw[k] & 0xffff0000u);
    }

    // leaky_relu(t) = 0.6t + 0.4|t|; fold log2(e) for base-2 exp
    float a6[8], a4[8];
    #pragma unroll
    for (int j = 0; j < 8; ++j) {
        const float a = att[c0 + j];
        a6[j] = a * (0.6f * LOG2E);
        a4[j] = a * (0.4f * LOG2E);
    }

    float dsum = 0.f;
    float p[8];
    #pragma unroll
    for (int j = 0; j < 8; ++j) p[j] = 0.f;

    const int beg = rowptr[n];
    const int dg  = deg[n];

    if (dg <= 64) {
        // --- fast path: all edge ids live in registers (one coalesced u16 load) ---
        const int myid = (lane < dg) ? (int)csr_src[beg + lane] : 0;
        const int nIter = (dg + 3) >> 2;

        auto ldrow = [&](int i) -> uint4v {
            const int j = 4 * i + q;
            const int s = __shfl(myid, (j < dg) ? j : 0);
            return *(const uint4v*)(xlb + ((size_t)s << 7) + c0);
        };
        // depth-3 software pipeline: 3 gathers in flight
        uint4v b0 = ldrow(0);
        uint4v b1 = ldrow(1);
        uint4v b2 = ldrow(2);

        for (int i = 0; i < nIter; ++i) {
            const uint4v cur = b0;
            b0 = b1; b1 = b2;
            b2 = ldrow(i + 3);
            const bool v = (4 * i + q) < dg;

            float x[8];
            #pragma unroll
            for (int k = 0; k < 4; ++k) {
                x[2 * k]     = __uint_as_float(cur[k] << 16);
                x[2 * k + 1] = __uint_as_float(cur[k] & 0xffff0000u);
            }
            float l = 0.f;
            #pragma unroll
            for (int j = 0; j < 8; ++j) {
                const float t = x[j] + xrv[j];
                l = fmaf(a6[j], t, fmaf(a4[j], fabsf(t), l));
            }
            l += __shfl_xor(l, 1);
            l += __shfl_xor(l, 2);
            l = v ? l : -INFINITY;
            const float w = exp2f(l);
            dsum += w;
            #pragma unroll
            for (int j = 0; j < 8; ++j) p[j] = fmaf(x[j], w, p[j]);
        }
    } else {
        // --- generic fallback (deg > 64): direct per-iteration id loads ---
        const int end = beg + dg;
        for (int e = beg; e < end; e += 4) {
            const int j = e + q;
            const bool v = (j < end);
            const int s = v ? (int)csr_src[j] : 0;
            const uint4v u = *(const uint4v*)(xlb + ((size_t)s << 7) + c0);
            float x[8];
            #pragma unroll
            for (int k = 0; k < 4; ++k) {
                x[2 * k]     = __uint_as_float(u[k] << 16);
                x[2 * k + 1] = __uint_as_float(u[k] & 0xffff0000u);
            }
            float l = 0.f;
            #pragma unroll
            for (int j2 = 0; j2 < 8; ++j2) {
                const float t = x[j2] + xrv[j2];
                l = fmaf(a6[j2], t, fmaf(a4[j2], fabsf(t), l));
            }
            l += __shfl_xor(l, 1);
            l += __shfl_xor(l, 2);
            l = v ? l : -INFINITY;
            const float w = exp2f(l);
            dsum += w;
            #pragma unroll
            for (int j2 = 0; j2 < 8; ++j2) p[j2] = fmaf(x[j2], w, p[j2]);
        }
    }

    // merge the 4 edge slots (quarters): xor 16, 32
    dsum += __shfl_xor(dsum, 16);
    dsum += __shfl_xor(dsum, 32);
    #pragma unroll
    for (int j = 0; j < 8; ++j) {
        p[j] += __shfl_xor(p[j], 16);
        p[j] += __shfl_xor(p[j], 32);
    }

    const float inv = 1.f / dsum;
    float v[8];
    float s2 = 0.f, sq = 0.f;
    #pragma unroll
    for (int j = 0; j < 8; ++j) {
        v[j] = p[j] * inv + bias[c0 + j];
        s2 += v[j];
        sq  = fmaf(v[j], v[j], sq);
    }
    // LN reduce across the 16 channel-groups (quarters are replicas)
    #pragma unroll
    for (int off = 1; off < 16; off <<= 1) {
        s2 += __shfl_xor(s2, off);
        sq += __shfl_xor(sq, off);
    }
    const float mu   = s2 * (1.f / 128.f);
    const float var  = sq * (1.f / 128.f) - mu * mu;
    const float rstd = rsqrtf(var + LN_EPS);

    if (q == 0) {
        float y[8];
        #pragma unroll
        for (int j = 0; j < 8; ++j)
            y[j] = gelu_exact((v[j] - mu) * rstd * gam[c0 + j] + bet[c0 + j]);
        float4 y0 = {y[0], y[1], y[2], y[3]};
        float4 y1 = {y[4], y[5], y[6], y[7]};
        *(float4*)(out + (size_t)n * DH + c0)     = y0;
        *(float4*)(out + (size_t)n * DH + c0 + 4) = y1;
    }
}

extern "C" void kernel_launch(void* const* d_in, const int* in_sizes, int n_in,
                              void* d_out, int out_size, void* d_ws, size_t ws_size,
                              hipStream_t stream)
{
    const float* x    = (const float*)d_in[0];
    const int*   eidx = (const int*)  d_in[1];

    const float* Wl[2]   = { (const float*)d_in[2],  (const float*)d_in[10] };
    const float* bl[2]   = { (const float*)d_in[3],  (const float*)d_in[11] };
    const float* Wr[2]   = { (const float*)d_in[4],  (const float*)d_in[12] };
    const float* br[2]   = { (const float*)d_in[5],  (const float*)d_in[13] };
    const float* att[2]  = { (const float*)d_in[6],  (const float*)d_in[14] };
    const float* bias[2] = { (const float*)d_in[7],  (const float*)d_in[15] };
    const float* gam[2]  = { (const float*)d_in[8],  (const float*)d_in[16] };
    const float* bet[2]  = { (const float*)d_in[9],  (const float*)d_in[17] };
    const float* Wout    = (const float*)d_in[18];
    const float* bout    = (const float*)d_in[19];
    const float* gout    = (const float*)d_in[20];
    const float* boutln  = (const float*)d_in[21];

    float* out = (float*)d_out;

    const size_t NF = (size_t)N_NODES * DH;
    unsigned short* xlb = (unsigned short*)d_ws;       // NF bf16 (gather operand)
    unsigned short* xrb = xlb + NF;                    // NF bf16
    float*          h1  = (float*)(xrb + NF);          // NF fp32
    float*          h2  = h1 + NF;
    unsigned short* csr_src = (unsigned short*)(h2 + NF);   // ETOT u16
    int*   deg     = (int*)(csr_src + ETOT + 16);
    int*   rowptr  = deg + N_NODES;
    int*   cursor  = rowptr + N_NODES;
    int*   bsum    = cursor + N_NODES;
    int*   boff    = bsum + NBLK;
    short* whi     = (short*)(boff + NBLK);   // 5 * 16384 shorts
    short* wlo     = whi + 5 * 16384;

    const int csrBlocks  = (ETOT / 4 + 255) / 256;   // 831
    const int nodeBlocks = N_NODES / 4;
    const int gemmBlocks = (N_NODES + MTILE - 1) / MTILE;   // 391

    #define WP(i) (whi + (i) * 16384), (wlo + (i) * 16384)

    // ---- CSR (deterministic rebuild every call) ----
    hipMemsetAsync(deg, 0, N_NODES * sizeof(int), stream);
    degree_kernel       <<<csrBlocks, 256, 0, stream>>>(eidx, deg);
    block_sum_kernel    <<<NBLK, 256, 0, stream>>>(deg, bsum);
    scan_partials_kernel<<<1, 256, 0, stream>>>(bsum, boff);
    rowptr_kernel       <<<NBLK, 256, 0, stream>>>(deg, boff, rowptr, cursor);
    scatter_kernel      <<<csrBlocks, 256, 0, stream>>>(eidx, cursor, csr_src);

    // ---- pack all 5 weight matrices ----
    pack_w_kernel<<<320, 256, 0, stream>>>(Wl[0], Wr[0], Wl[1], Wr[1], Wout, whi, wlo);

    // ---- layer 0 ----
    gemm_mfma_kernel<<<dim3(gemmBlocks, 2), 256, 0, stream>>>(
        x, N_NODES, WP(0), bl[0], xlb, WP(1), br[0], xrb);
    gat_node_kernel<<<nodeBlocks, 256, 0, stream>>>(rowptr, deg, csr_src, xlb, xrb,
                                                    att[0], bias[0], gam[0], bet[0], h1);
    // ---- layer 1 ----
    gemm_mfma_kernel<<<dim3(gemmBlocks, 2), 256, 0, stream>>>(
        h1, N_NODES, WP(2), bl[1], xlb, WP(3), br[1], xrb);
    gat_node_kernel<<<nodeBlocks, 256, 0, stream>>>(rowptr, deg, csr_src, xlb, xrb,
                                                    att[1], bias[1], gam[1], bet[1], h2);

    // ---- output projection + fused final LayerNorm ----
    gemm1_ln_kernel<<<gemmBlocks, 256, 0, stream>>>(
        h2, N_NODES, WP(4), bout, gout, boutln, out);
}

// Round 14
// 289.868 us; speedup vs baseline: 1.0292x; 1.0292x over previous
//
#include <hip/hip_runtime.h>
#include <math.h>

#define N_NODES 50000
#define N_EDGES 800000
#define ETOT    (N_EDGES + N_NODES)
#define DH      128
#define NH      4
#define LN_EPS  1e-5f
#define NBLK    ((N_NODES + 255) / 256)   // 196 scan blocks
#define LOG2E   1.4426950408889634f

typedef __attribute__((ext_vector_type(8))) short short8;
typedef __attribute__((ext_vector_type(8))) unsigned short ushort8v;
typedef __attribute__((ext_vector_type(4))) float f32x4;
typedef __attribute__((ext_vector_type(4))) unsigned uint4v;

// ---------- fp32 -> bf16 (RNE) helpers ----------
__device__ __forceinline__ unsigned short f2bf(float f) {
    unsigned u = __float_as_uint(f);
    u += 0x7FFFu + ((u >> 16) & 1u);
    return (unsigned short)(u >> 16);
}
__device__ __forceinline__ float bf2f(unsigned short h) {
    return __uint_as_float(((unsigned)h) << 16);
}
// pack two fp32 -> u32 of 2 bf16 (RNE), low short = a
__device__ __forceinline__ unsigned pk_bf16(float a, float b) {
    unsigned h;
    asm("v_cvt_pk_bf16_f32 %0, %1, %2" : "=v"(h) : "v"(a), "v"(b));
    return h;
}

// ---------- fast exact-GELU (A&S 7.1.26 erf, max err ~1.5e-7) ----------
__device__ __forceinline__ float gelu_exact(float x) {
    const float z  = x * 0.70710678118654752f;
    const float az = fabsf(z);
    const float tt = __builtin_amdgcn_rcpf(fmaf(0.3275911f, az, 1.f));
    float p = fmaf(1.061405429f, tt, -1.453152027f);
    p = fmaf(p, tt, 1.421413741f);
    p = fmaf(p, tt, -0.284496736f);
    p = fmaf(p, tt, 0.254829592f);
    p = p * tt;
    const float ez = exp2f(-(z * z) * LOG2E);
    float er = fmaf(-p, ez, 1.f);
    er = copysignf(er, z);
    return x * fmaf(0.5f, er, 0.5f);
}

// ========== prep: pack 5 W matrices (hi/lo) + convert x to bf16 ==========
// blocks 0..319: weight packing; blocks 320..3444: x conversion
__global__ __launch_bounds__(256) void prep_kernel(
    const float* __restrict__ W0, const float* __restrict__ W1,
    const float* __restrict__ W2, const float* __restrict__ W3,
    const float* __restrict__ W4,
    short* __restrict__ hi, short* __restrict__ lo,
    const float* __restrict__ X, unsigned short* __restrict__ Xb)
{
    const int b = blockIdx.x;
    if (b < 320) {
        const int idx = b * 256 + threadIdx.x;   // 0..81919
        const int mat = idx >> 14;
        const int rem = idx & 16383;
        const int t = rem >> 12, c = (rem >> 9) & 7, l = (rem >> 3) & 63, j = rem & 7;
        const int k = t * 32 + (l >> 4) * 8 + j;
        const int n = c * 16 + (l & 15);
        const float* W = (mat == 0) ? W0 : (mat == 1) ? W1 : (mat == 2) ? W2
                       : (mat == 3) ? W3 : W4;
        const float v = W[k * DH + n];
        const unsigned short h = f2bf(v);
        hi[idx] = (short)h;
        lo[idx] = (short)f2bf(v - bf2f(h));
    } else {
        const size_t i = ((size_t)(b - 320) * 256 + threadIdx.x) * 8;   // NF = 3125*2048
        const float4 f0 = *(const float4*)(X + i);
        const float4 f1 = *(const float4*)(X + i + 4);
        uint4v o;
        o[0] = pk_bf16(f0.x, f0.y);
        o[1] = pk_bf16(f0.z, f0.w);
        o[2] = pk_bf16(f1.x, f1.y);
        o[3] = pk_bf16(f1.z, f1.w);
        *(uint4v*)(Xb + i) = o;
    }
}

// ========== bf16-A x split-W MFMA GEMM; bf16 outputs ==========
// blockIdx.y==0: YL = A@Wl+bl ; blockIdx.y==1: YR = A@Wr+br
#define MTILE 128
__global__ __launch_bounds__(256) void gemm_mfma_kernel(
    const unsigned short* __restrict__ A, int m_rows,
    const short* __restrict__ WhiL, const short* __restrict__ WloL,
    const float* __restrict__ biasL, unsigned short* __restrict__ YL,
    const short* __restrict__ WhiR, const short* __restrict__ WloR,
    const float* __restrict__ biasR, unsigned short* __restrict__ YR)
{
    const int w    = threadIdx.x >> 6;
    const int lane = threadIdx.x & 63;
    const short* Whi  = blockIdx.y ? WhiR  : WhiL;
    const short* Wlo  = blockIdx.y ? WloR  : WloL;
    const float* bias = blockIdx.y ? biasR : biasL;
    unsigned short* Y = blockIdx.y ? YR    : YL;

    const int rows0 = blockIdx.x * MTILE + w * 32;
    const int g  = lane >> 4;
    const int rl = lane & 15;

    f32x4 acc[2][8];
    #pragma unroll
    for (int r = 0; r < 2; ++r)
        #pragma unroll
        for (int c = 0; c < 8; ++c)
            acc[r][c] = (f32x4){0.f, 0.f, 0.f, 0.f};

    for (int t = 0; t < 4; ++t) {
        short8 ahi[2];
        #pragma unroll
        for (int r = 0; r < 2; ++r) {
            int arow = rows0 + 16 * r + rl;
            arow = (arow < m_rows) ? arow : (m_rows - 1);
            ahi[r] = *(const short8*)(A + (size_t)arow * DH + t * 32 + g * 8);
        }
        #pragma unroll
        for (int c = 0; c < 8; ++c) {
            const int fidx = ((t * 8 + c) * 64 + lane) * 8;
            const short8 bhi = *(const short8*)(Whi + fidx);
            const short8 blo = *(const short8*)(Wlo + fidx);
            acc[0][c] = __builtin_amdgcn_mfma_f32_16x16x32_bf16(ahi[0], bhi, acc[0][c], 0, 0, 0);
            acc[1][c] = __builtin_amdgcn_mfma_f32_16x16x32_bf16(ahi[1], bhi, acc[1][c], 0, 0, 0);
            acc[0][c] = __builtin_amdgcn_mfma_f32_16x16x32_bf16(ahi[0], blo, acc[0][c], 0, 0, 0);
            acc[1][c] = __builtin_amdgcn_mfma_f32_16x16x32_bf16(ahi[1], blo, acc[1][c], 0, 0, 0);
        }
    }
    #pragma unroll
    for (int c = 0; c < 8; ++c) {
        const int col = c * 16 + rl;
        const float bb = bias[col];
        #pragma unroll
        for (int r = 0; r < 2; ++r) {
            #pragma unroll
            for (int q = 0; q < 4; ++q) {
                const int row = rows0 + 16 * r + g * 4 + q;
                if (row < m_rows)
                    Y[(size_t)row * DH + col] = f2bf(acc[r][c][q] + bb);
            }
        }
    }
}

// ========== gemm1 + fused final LayerNorm: out = LN(A@W + b; g, bt), bf16 A ==========
__global__ __launch_bounds__(256) void gemm1_ln_kernel(
    const unsigned short* __restrict__ A, int m_rows,
    const short* __restrict__ Whi, const short* __restrict__ Wlo,
    const float* __restrict__ bias,
    const float* __restrict__ gam, const float* __restrict__ bet,
    float* __restrict__ out)
{
    const int w    = threadIdx.x >> 6;
    const int lane = threadIdx.x & 63;
    const int rows0 = blockIdx.x * MTILE + w * 32;
    const int g  = lane >> 4;
    const int rl = lane & 15;

    f32x4 acc[2][8];
    #pragma unroll
    for (int r = 0; r < 2; ++r)
        #pragma unroll
        for (int c = 0; c < 8; ++c)
            acc[r][c] = (f32x4){0.f, 0.f, 0.f, 0.f};

    for (int t = 0; t < 4; ++t) {
        short8 ahi[2];
        #pragma unroll
        for (int r = 0; r < 2; ++r) {
            int arow = rows0 + 16 * r + rl;
            arow = (arow < m_rows) ? arow : (m_rows - 1);
            ahi[r] = *(const short8*)(A + (size_t)arow * DH + t * 32 + g * 8);
        }
        #pragma unroll
        for (int c = 0; c < 8; ++c) {
            const int fidx = ((t * 8 + c) * 64 + lane) * 8;
            const short8 bh = *(const short8*)(Whi + fidx);
            const short8 bl = *(const short8*)(Wlo + fidx);
            acc[0][c] = __builtin_amdgcn_mfma_f32_16x16x32_bf16(ahi[0], bh, acc[0][c], 0, 0, 0);
            acc[1][c] = __builtin_amdgcn_mfma_f32_16x16x32_bf16(ahi[1], bh, acc[1][c], 0, 0, 0);
            acc[0][c] = __builtin_amdgcn_mfma_f32_16x16x32_bf16(ahi[0], bl, acc[0][c], 0, 0, 0);
            acc[1][c] = __builtin_amdgcn_mfma_f32_16x16x32_bf16(ahi[1], bl, acc[1][c], 0, 0, 0);
        }
    }

    float bb[8], gg[8], bt8[8];
    #pragma unroll
    for (int c = 0; c < 8; ++c) {
        const int col = c * 16 + rl;
        bb[c] = bias[col];  gg[c] = gam[col];  bt8[c] = bet[col];
    }
    #pragma unroll
    for (int r = 0; r < 2; ++r) {
        #pragma unroll
        for (int q = 0; q < 4; ++q) {
            float v[8];
            float s = 0.f, sq = 0.f;
            #pragma unroll
            for (int c = 0; c < 8; ++c) {
                v[c] = acc[r][c][q] + bb[c];
                s  += v[c];
                sq  = fmaf(v[c], v[c], sq);
            }
            #pragma unroll
            for (int off = 1; off < 16; off <<= 1) {
                s  += __shfl_xor(s,  off);
                sq += __shfl_xor(sq, off);
            }
            const float mu   = s * (1.f / 128.f);
            const float var  = sq * (1.f / 128.f) - mu * mu;
            const float rstd = rsqrtf(var + LN_EPS);
            const int row = rows0 + 16 * r + g * 4 + q;
            if (row < m_rows) {
                #pragma unroll
                for (int c = 0; c < 8; ++c)
                    out[(size_t)row * DH + c * 16 + rl] =
                        (v[c] - mu) * rstd * gg[c] + bt8[c];
            }
        }
    }
}

// ========================= CSR construction (4-edge ILP) =========================
__global__ __launch_bounds__(256) void degree_kernel(
    const int* __restrict__ eidx, int* __restrict__ deg)
{
    const int base = (blockIdx.x * 256 + threadIdx.x) * 4;
    if (base < N_EDGES) {
        const int4 dv = *(const int4*)(eidx + N_EDGES + base);
        atomicAdd(&deg[dv.x], 1);
        atomicAdd(&deg[dv.y], 1);
        atomicAdd(&deg[dv.z], 1);
        atomicAdd(&deg[dv.w], 1);
    } else if (base < ETOT) {
        const int d0 = base - N_EDGES;
        atomicAdd(&deg[d0], 1);
        atomicAdd(&deg[d0 + 1], 1);
        atomicAdd(&deg[d0 + 2], 1);
        atomicAdd(&deg[d0 + 3], 1);
    }
}

__global__ __launch_bounds__(256) void block_sum_kernel(
    const int* __restrict__ deg, int* __restrict__ bsum)
{
    const int i    = blockIdx.x * 256 + threadIdx.x;
    const int lane = threadIdx.x & 63;
    const int wid  = threadIdx.x >> 6;
    int v = (i < N_NODES) ? deg[i] : 0;
    #pragma unroll
    for (int off = 32; off; off >>= 1) v += __shfl_xor(v, off);
    __shared__ int ws[4];
    if (lane == 0) ws[wid] = v;
    __syncthreads();
    if (threadIdx.x == 0) bsum[blockIdx.x] = ws[0] + ws[1] + ws[2] + ws[3];
}

__global__ __launch_bounds__(256) void scan_partials_kernel(
    const int* __restrict__ bsum, int* __restrict__ boff)
{
    const int t    = threadIdx.x;
    const int lane = t & 63;
    const int wid  = t >> 6;
    int v = (t < NBLK) ? bsum[t] : 0;
    int inc = v;
    #pragma unroll
    for (int off = 1; off < 64; off <<= 1) {
        int u = __shfl_up(inc, off);
        if (lane >= off) inc += u;
    }
    __shared__ int ws[4];
    if (lane == 63) ws[wid] = inc;
    __syncthreads();
    int add = 0;
    for (int w = 0; w < wid; ++w) add += ws[w];
    if (t < NBLK) boff[t] = add + inc - v;
}

__global__ __launch_bounds__(256) void rowptr_kernel(
    const int* __restrict__ deg, const int* __restrict__ boff,
    int* __restrict__ rowptr, int* __restrict__ cursor)
{
    const int i    = blockIdx.x * 256 + threadIdx.x;
    const int lane = threadIdx.x & 63;
    const int wid  = threadIdx.x >> 6;
    int v = (i < N_NODES) ? deg[i] : 0;
    int inc = v;
    #pragma unroll
    for (int off = 1; off < 64; off <<= 1) {
        int u = __shfl_up(inc, off);
        if (lane >= off) inc += u;
    }
    __shared__ int ws[4];
    if (lane == 63) ws[wid] = inc;
    __syncthreads();
    int add = boff[blockIdx.x];
    for (int w = 0; w < wid; ++w) add += ws[w];
    if (i < N_NODES) {
        const int ex = add + inc - v;
        rowptr[i] = ex;
        cursor[i] = ex;
    }
}

__global__ __launch_bounds__(256) void scatter_kernel(
    const int* __restrict__ eidx, int* __restrict__ cursor,
    unsigned short* __restrict__ csr_src)
{
    const int base = (blockIdx.x * 256 + threadIdx.x) * 4;
    if (base < N_EDGES) {
        const int4 sv = *(const int4*)(eidx + base);
        const int4 dv = *(const int4*)(eidx + N_EDGES + base);
        const int t0 = atomicAdd(&cursor[dv.x], 1);
        const int t1 = atomicAdd(&cursor[dv.y], 1);
        const int t2 = atomicAdd(&cursor[dv.z], 1);
        const int t3 = atomicAdd(&cursor[dv.w], 1);
        csr_src[t0] = (unsigned short)sv.x;
        csr_src[t1] = (unsigned short)sv.y;
        csr_src[t2] = (unsigned short)sv.z;
        csr_src[t3] = (unsigned short)sv.w;
    } else if (base < ETOT) {
        const int d0 = base - N_EDGES;
        const int t0 = atomicAdd(&cursor[d0], 1);
        const int t1 = atomicAdd(&cursor[d0 + 1], 1);
        const int t2 = atomicAdd(&cursor[d0 + 2], 1);
        const int t3 = atomicAdd(&cursor[d0 + 3], 1);
        csr_src[t0] = (unsigned short)d0;
        csr_src[t1] = (unsigned short)(d0 + 1);
        csr_src[t2] = (unsigned short)(d0 + 2);
        csr_src[t3] = (unsigned short)(d0 + 3);
    }
}

// ====== fused per-node GAT (R9 best form): 16 lanes/edge, prefetch-1, bf16 out ======
__global__ __launch_bounds__(256) void gat_node_kernel(
    const int* __restrict__ rowptr, const int* __restrict__ deg,
    const unsigned short* __restrict__ csr_src,
    const unsigned short* __restrict__ xlb, const unsigned short* __restrict__ xrb,
    const float* __restrict__ att, const float* __restrict__ bias,
    const float* __restrict__ gam, const float* __restrict__ bet,
    unsigned short* __restrict__ out)
{
    const int n    = blockIdx.x * 4 + (threadIdx.x >> 6);
    const int lane = threadIdx.x & 63;
    if (n >= N_NODES) return;
    const int q  = lane >> 4;       // edge slot 0..3
    const int r  = lane & 15;       // channel group
    const int c0 = r * 8;

    const ushort8v ur = *(const ushort8v*)(xrb + ((size_t)n << 7) + c0);
    float xrv[8];
    #pragma unroll
    for (int j = 0; j < 8; ++j) xrv[j] = bf2f(ur[j]);

    float a6[8], a4[8];
    #pragma unroll
    for (int j = 0; j < 8; ++j) {
        const float a = att[c0 + j];
        a6[j] = a * (0.6f * LOG2E);
        a4[j] = a * (0.4f * LOG2E);
    }

    float dsum = 0.f;
    float p[8];
    #pragma unroll
    for (int j = 0; j < 8; ++j) p[j] = 0.f;

    const int beg = rowptr[n];
    const int end = beg + deg[n];

    int e = beg;
    bool vcur = (e + q) < end;
    int s = vcur ? (int)csr_src[e + q] : 0;
    ushort8v u = *(const ushort8v*)(xlb + ((size_t)s << 7) + c0);

    while (e < end) {
        const int en = e + 4;
        ushort8v unext = u;
        bool vnext = false;
        if (en < end) {   // wave-uniform
            vnext = (en + q) < end;
            const int sn = vnext ? (int)csr_src[en + q] : 0;
            unext = *(const ushort8v*)(xlb + ((size_t)sn << 7) + c0);
        }
        float x[8];
        #pragma unroll
        for (int j = 0; j < 8; ++j) x[j] = bf2f(u[j]);
        float l = 0.f;
        #pragma unroll
        for (int j = 0; j < 8; ++j) {
            const float t = x[j] + xrv[j];
            l = fmaf(a6[j], t, fmaf(a4[j], fabsf(t), l));
        }
        l += __shfl_xor(l, 1);
        l += __shfl_xor(l, 2);
        l = vcur ? l : -INFINITY;
        const float w = exp2f(l);
        dsum += w;
        #pragma unroll
        for (int j = 0; j < 8; ++j) p[j] = fmaf(x[j], w, p[j]);

        u = unext; vcur = vnext; e = en;
    }

    dsum += __shfl_xor(dsum, 16);
    dsum += __shfl_xor(dsum, 32);
    #pragma unroll
    for (int j = 0; j < 8; ++j) {
        p[j] += __shfl_xor(p[j], 16);
        p[j] += __shfl_xor(p[j], 32);
    }

    const float inv = 1.f / dsum;
    float v[8];
    float s2 = 0.f, sq = 0.f;
    #pragma unroll
    for (int j = 0; j < 8; ++j) {
        v[j] = p[j] * inv + bias[c0 + j];
        s2 += v[j];
        sq  = fmaf(v[j], v[j], sq);
    }
    #pragma unroll
    for (int off = 1; off < 16; off <<= 1) {
        s2 += __shfl_xor(s2, off);
        sq += __shfl_xor(sq, off);
    }
    const float mu   = s2 * (1.f / 128.f);
    const float var  = sq * (1.f / 128.f) - mu * mu;
    const float rstd = rsqrtf(var + LN_EPS);

    if (q == 0) {
        float y[8];
        #pragma unroll
        for (int j = 0; j < 8; ++j)
            y[j] = gelu_exact((v[j] - mu) * rstd * gam[c0 + j] + bet[c0 + j]);
        uint4v o;
        o[0] = pk_bf16(y[0], y[1]);
        o[1] = pk_bf16(y[2], y[3]);
        o[2] = pk_bf16(y[4], y[5]);
        o[3] = pk_bf16(y[6], y[7]);
        *(uint4v*)(out + ((size_t)n << 7) + c0) = o;
    }
}

extern "C" void kernel_launch(void* const* d_in, const int* in_sizes, int n_in,
                              void* d_out, int out_size, void* d_ws, size_t ws_size,
                              hipStream_t stream)
{
    const float* x    = (const float*)d_in[0];
    const int*   eidx = (const int*)  d_in[1];

    const float* Wl[2]   = { (const float*)d_in[2],  (const float*)d_in[10] };
    const float* bl[2]   = { (const float*)d_in[3],  (const float*)d_in[11] };
    const float* Wr[2]   = { (const float*)d_in[4],  (const float*)d_in[12] };
    const float* br[2]   = { (const float*)d_in[5],  (const float*)d_in[13] };
    const float* att[2]  = { (const float*)d_in[6],  (const float*)d_in[14] };
    const float* bias[2] = { (const float*)d_in[7],  (const float*)d_in[15] };
    const float* gam[2]  = { (const float*)d_in[8],  (const float*)d_in[16] };
    const float* bet[2]  = { (const float*)d_in[9],  (const float*)d_in[17] };
    const float* Wout    = (const float*)d_in[18];
    const float* bout    = (const float*)d_in[19];
    const float* gout    = (const float*)d_in[20];
    const float* boutln  = (const float*)d_in[21];

    float* out = (float*)d_out;

    const size_t NF = (size_t)N_NODES * DH;
    unsigned short* xb  = (unsigned short*)d_ws;       // NF bf16 (x converted)
    unsigned short* xlb = xb + NF;                     // NF bf16 (gather operand)
    unsigned short* xrb = xlb + NF;                    // NF bf16
    unsigned short* hb  = xrb + NF;                    // NF bf16 (hidden act)
    unsigned short* csr_src = hb + NF;                 // ETOT u16
    int*   deg     = (int*)(csr_src + ETOT + 16);
    int*   rowptr  = deg + N_NODES;
    int*   cursor  = rowptr + N_NODES;
    int*   bsum    = cursor + N_NODES;
    int*   boff    = bsum + NBLK;
    short* whi     = (short*)(boff + NBLK);   // 5 * 16384 shorts
    short* wlo     = whi + 5 * 16384;

    const int csrBlocks  = (ETOT / 4 + 255) / 256;   // 831
    const int nodeBlocks = N_NODES / 4;
    const int gemmBlocks = (N_NODES + MTILE - 1) / MTILE;   // 391
    const int prepBlocks = 320 + (int)(NF / 2048);          // 320 + 3125

    #define WP(i) (whi + (i) * 16384), (wlo + (i) * 16384)

    // ---- CSR (deterministic rebuild every call) ----
    hipMemsetAsync(deg, 0, N_NODES * sizeof(int), stream);
    degree_kernel       <<<csrBlocks, 256, 0, stream>>>(eidx, deg);
    block_sum_kernel    <<<NBLK, 256, 0, stream>>>(deg, bsum);
    scan_partials_kernel<<<1, 256, 0, stream>>>(bsum, boff);
    rowptr_kernel       <<<NBLK, 256, 0, stream>>>(deg, boff, rowptr, cursor);
    scatter_kernel      <<<csrBlocks, 256, 0, stream>>>(eidx, cursor, csr_src);

    // ---- pack weights + convert x to bf16 (single launch) ----
    prep_kernel<<<prepBlocks, 256, 0, stream>>>(Wl[0], Wr[0], Wl[1], Wr[1], Wout,
                                                whi, wlo, x, xb);

    // ---- layer 0 ----
    gemm_mfma_kernel<<<dim3(gemmBlocks, 2), 256, 0, stream>>>(
        xb, N_NODES, WP(0), bl[0], xlb, WP(1), br[0], xrb);
    gat_node_kernel<<<nodeBlocks, 256, 0, stream>>>(rowptr, deg, csr_src, xlb, xrb,
                                                    att[0], bias[0], gam[0], bet[0], hb);
    // ---- layer 1 ----
    gemm_mfma_kernel<<<dim3(gemmBlocks, 2), 256, 0, stream>>>(
        hb, N_NODES, WP(2), bl[1], xlb, WP(3), br[1], xrb);
    gat_node_kernel<<<nodeBlocks, 256, 0, stream>>>(rowptr, deg, csr_src, xlb, xrb,
                                                    att[1], bias[1], gam[1], bet[1], hb);

    // ---- output projection + fused final LayerNorm ----
    gemm1_ln_kernel<<<gemmBlocks, 256, 0, stream>>>(
        hb, N_NODES, WP(4), bout, gout, boutln, out);
}

// Round 15
// 271.796 us; speedup vs baseline: 1.0976x; 1.0665x over previous
//
#include <hip/hip_runtime.h>
#include <math.h>

#define N_NODES 50000
#define N_EDGES 800000
#define ETOT    (N_EDGES + N_NODES)
#define DH      128
#define NH      4
#define LN_EPS  1e-5f
#define NBLK    ((N_NODES + 255) / 256)   // 196 scan blocks
#define LOG2E   1.4426950408889634f

typedef __attribute__((ext_vector_type(8))) short short8;
typedef __attribute__((ext_vector_type(8))) unsigned short ushort8v;
typedef __attribute__((ext_vector_type(4))) float f32x4;
typedef __attribute__((ext_vector_type(4))) unsigned uint4v;

// ---------- fp32 -> bf16 (RNE) helpers ----------
__device__ __forceinline__ unsigned short f2bf(float f) {
    unsigned u = __float_as_uint(f);
    u += 0x7FFFu + ((u >> 16) & 1u);
    return (unsigned short)(u >> 16);
}
__device__ __forceinline__ float bf2f(unsigned short h) {
    return __uint_as_float(((unsigned)h) << 16);
}
__device__ __forceinline__ unsigned pk_bf16(float a, float b) {
    unsigned h;
    asm("v_cvt_pk_bf16_f32 %0, %1, %2" : "=v"(h) : "v"(a), "v"(b));
    return h;
}

// ---------- fast exact-GELU (A&S 7.1.26 erf, max err ~1.5e-7) ----------
__device__ __forceinline__ float gelu_exact(float x) {
    const float z  = x * 0.70710678118654752f;
    const float az = fabsf(z);
    const float tt = __builtin_amdgcn_rcpf(fmaf(0.3275911f, az, 1.f));
    float p = fmaf(1.061405429f, tt, -1.453152027f);
    p = fmaf(p, tt, 1.421413741f);
    p = fmaf(p, tt, -0.284496736f);
    p = fmaf(p, tt, 0.254829592f);
    p = p * tt;
    const float ez = exp2f(-(z * z) * LOG2E);
    float er = fmaf(-p, ez, 1.f);
    er = copysignf(er, z);
    return x * fmaf(0.5f, er, 0.5f);
}

// ========== prep: pack 5 W (hi/lo) + convert x to bf16 + zero deg ==========
__global__ __launch_bounds__(256) void prep_kernel(
    const float* __restrict__ W0, const float* __restrict__ W1,
    const float* __restrict__ W2, const float* __restrict__ W3,
    const float* __restrict__ W4,
    short* __restrict__ hi, short* __restrict__ lo,
    const float* __restrict__ X, unsigned short* __restrict__ Xb,
    int* __restrict__ deg)
{
    const int b = blockIdx.x;
    if (b < 320) {
        const int idx = b * 256 + threadIdx.x;   // 0..81919
        const int mat = idx >> 14;
        const int rem = idx & 16383;
        const int t = rem >> 12, c = (rem >> 9) & 7, l = (rem >> 3) & 63, j = rem & 7;
        const int k = t * 32 + (l >> 4) * 8 + j;
        const int n = c * 16 + (l & 15);
        const float* W = (mat == 0) ? W0 : (mat == 1) ? W1 : (mat == 2) ? W2
                       : (mat == 3) ? W3 : W4;
        const float v = W[k * DH + n];
        const unsigned short h = f2bf(v);
        hi[idx] = (short)h;
        lo[idx] = (short)f2bf(v - bf2f(h));
    } else {
        const int xb_blk = b - 320;
        const int tid = xb_blk * 256 + threadIdx.x;
        const size_t i = (size_t)tid * 8;   // NF = 3125*2048
        const float4 f0 = *(const float4*)(X + i);
        const float4 f1 = *(const float4*)(X + i + 4);
        uint4v o;
        o[0] = pk_bf16(f0.x, f0.y);
        o[1] = pk_bf16(f0.z, f0.w);
        o[2] = pk_bf16(f1.x, f1.y);
        o[3] = pk_bf16(f1.z, f1.w);
        *(uint4v*)(Xb + i) = o;
        if (tid < N_NODES) deg[tid] = 0;
    }
}

// ========== fused dual GEMM, column-split: 16 rows/wave, both L and R ==========
// blockIdx.y = column half (64 cols); A-fragment loaded once, used for 4 MFMAs/c
#define GTILE 64
__global__ __launch_bounds__(256) void gemm2_kernel(
    const unsigned short* __restrict__ A, int m_rows,
    const short* __restrict__ WhiL, const short* __restrict__ WloL,
    const float* __restrict__ biasL, unsigned short* __restrict__ YL,
    const short* __restrict__ WhiR, const short* __restrict__ WloR,
    const float* __restrict__ biasR, unsigned short* __restrict__ YR)
{
    const int w    = threadIdx.x >> 6;
    const int lane = threadIdx.x & 63;
    const int rows0 = blockIdx.x * GTILE + w * 16;
    const int ch   = blockIdx.y;          // column half 0/1
    const int g  = lane >> 4;
    const int rl = lane & 15;

    f32x4 accL[4], accR[4];
    #pragma unroll
    for (int c = 0; c < 4; ++c) {
        accL[c] = (f32x4){0.f, 0.f, 0.f, 0.f};
        accR[c] = (f32x4){0.f, 0.f, 0.f, 0.f};
    }

    for (int t = 0; t < 4; ++t) {
        int arow = rows0 + rl;
        arow = (arow < m_rows) ? arow : (m_rows - 1);
        const short8 a = *(const short8*)(A + (size_t)arow * DH + t * 32 + g * 8);
        #pragma unroll
        for (int c = 0; c < 4; ++c) {
            const int cc = ch * 4 + c;
            const int fidx = ((t * 8 + cc) * 64 + lane) * 8;
            const short8 bhL = *(const short8*)(WhiL + fidx);
            const short8 blL = *(const short8*)(WloL + fidx);
            const short8 bhR = *(const short8*)(WhiR + fidx);
            const short8 blR = *(const short8*)(WloR + fidx);
            accL[c] = __builtin_amdgcn_mfma_f32_16x16x32_bf16(a, bhL, accL[c], 0, 0, 0);
            accL[c] = __builtin_amdgcn_mfma_f32_16x16x32_bf16(a, blL, accL[c], 0, 0, 0);
            accR[c] = __builtin_amdgcn_mfma_f32_16x16x32_bf16(a, bhR, accR[c], 0, 0, 0);
            accR[c] = __builtin_amdgcn_mfma_f32_16x16x32_bf16(a, blR, accR[c], 0, 0, 0);
        }
    }
    #pragma unroll
    for (int c = 0; c < 4; ++c) {
        const int col = (ch * 4 + c) * 16 + rl;
        const float bL = biasL[col];
        const float bR = biasR[col];
        #pragma unroll
        for (int q = 0; q < 4; ++q) {
            const int row = rows0 + g * 4 + q;
            if (row < m_rows) {
                YL[(size_t)row * DH + col] = f2bf(accL[c][q] + bL);
                YR[(size_t)row * DH + col] = f2bf(accR[c][q] + bR);
            }
        }
    }
}

// ========== gemm1 + fused final LayerNorm: 16 rows/wave ==========
__global__ __launch_bounds__(256) void gemm1_ln_kernel(
    const unsigned short* __restrict__ A, int m_rows,
    const short* __restrict__ Whi, const short* __restrict__ Wlo,
    const float* __restrict__ bias,
    const float* __restrict__ gam, const float* __restrict__ bet,
    float* __restrict__ out)
{
    const int w    = threadIdx.x >> 6;
    const int lane = threadIdx.x & 63;
    const int rows0 = blockIdx.x * GTILE + w * 16;
    const int g  = lane >> 4;
    const int rl = lane & 15;

    f32x4 acc[8];
    #pragma unroll
    for (int c = 0; c < 8; ++c)
        acc[c] = (f32x4){0.f, 0.f, 0.f, 0.f};

    for (int t = 0; t < 4; ++t) {
        int arow = rows0 + rl;
        arow = (arow < m_rows) ? arow : (m_rows - 1);
        const short8 a = *(const short8*)(A + (size_t)arow * DH + t * 32 + g * 8);
        #pragma unroll
        for (int c = 0; c < 8; ++c) {
            const int fidx = ((t * 8 + c) * 64 + lane) * 8;
            const short8 bh = *(const short8*)(Whi + fidx);
            const short8 bl = *(const short8*)(Wlo + fidx);
            acc[c] = __builtin_amdgcn_mfma_f32_16x16x32_bf16(a, bh, acc[c], 0, 0, 0);
            acc[c] = __builtin_amdgcn_mfma_f32_16x16x32_bf16(a, bl, acc[c], 0, 0, 0);
        }
    }

    float bb[8], gg[8], bt8[8];
    #pragma unroll
    for (int c = 0; c < 8; ++c) {
        const int col = c * 16 + rl;
        bb[c] = bias[col];  gg[c] = gam[col];  bt8[c] = bet[col];
    }
    #pragma unroll
    for (int q = 0; q < 4; ++q) {
        float v[8];
        float s = 0.f, sq = 0.f;
        #pragma unroll
        for (int c = 0; c < 8; ++c) {
            v[c] = acc[c][q] + bb[c];
            s  += v[c];
            sq  = fmaf(v[c], v[c], sq);
        }
        #pragma unroll
        for (int off = 1; off < 16; off <<= 1) {
            s  += __shfl_xor(s,  off);
            sq += __shfl_xor(sq, off);
        }
        const float mu   = s * (1.f / 128.f);
        const float var  = sq * (1.f / 128.f) - mu * mu;
        const float rstd = rsqrtf(var + LN_EPS);
        const int row = rows0 + g * 4 + q;
        if (row < m_rows) {
            #pragma unroll
            for (int c = 0; c < 8; ++c)
                out[(size_t)row * DH + c * 16 + rl] =
                    (v[c] - mu) * rstd * gg[c] + bt8[c];
        }
    }
}

// ========================= CSR construction (8-edge ILP) =========================
// N_EDGES % 8 == 0, (ETOT-N_EDGES) % 8 == 0: chunks never straddle regions.
__global__ __launch_bounds__(256) void degree_kernel(
    const int* __restrict__ eidx, int* __restrict__ deg)
{
    const int base = (blockIdx.x * 256 + threadIdx.x) * 8;
    if (base < N_EDGES) {
        const int4 d0 = *(const int4*)(eidx + N_EDGES + base);
        const int4 d1 = *(const int4*)(eidx + N_EDGES + base + 4);
        atomicAdd(&deg[d0.x], 1);
        atomicAdd(&deg[d0.y], 1);
        atomicAdd(&deg[d0.z], 1);
        atomicAdd(&deg[d0.w], 1);
        atomicAdd(&deg[d1.x], 1);
        atomicAdd(&deg[d1.y], 1);
        atomicAdd(&deg[d1.z], 1);
        atomicAdd(&deg[d1.w], 1);
    } else if (base < ETOT) {
        const int d0 = base - N_EDGES;
        #pragma unroll
        for (int k = 0; k < 8; ++k) atomicAdd(&deg[d0 + k], 1);
    }
}

__global__ __launch_bounds__(256) void block_sum_kernel(
    const int* __restrict__ deg, int* __restrict__ bsum)
{
    const int i    = blockIdx.x * 256 + threadIdx.x;
    const int lane = threadIdx.x & 63;
    const int wid  = threadIdx.x >> 6;
    int v = (i < N_NODES) ? deg[i] : 0;
    #pragma unroll
    for (int off = 32; off; off >>= 1) v += __shfl_xor(v, off);
    __shared__ int ws[4];
    if (lane == 0) ws[wid] = v;
    __syncthreads();
    if (threadIdx.x == 0) bsum[blockIdx.x] = ws[0] + ws[1] + ws[2] + ws[3];
}

__global__ __launch_bounds__(256) void scan_partials_kernel(
    const int* __restrict__ bsum, int* __restrict__ boff)
{
    const int t    = threadIdx.x;
    const int lane = t & 63;
    const int wid  = t >> 6;
    int v = (t < NBLK) ? bsum[t] : 0;
    int inc = v;
    #pragma unroll
    for (int off = 1; off < 64; off <<= 1) {
        int u = __shfl_up(inc, off);
        if (lane >= off) inc += u;
    }
    __shared__ int ws[4];
    if (lane == 63) ws[wid] = inc;
    __syncthreads();
    int add = 0;
    for (int w = 0; w < wid; ++w) add += ws[w];
    if (t < NBLK) boff[t] = add + inc - v;
}

__global__ __launch_bounds__(256) void rowptr_kernel(
    const int* __restrict__ deg, const int* __restrict__ boff,
    int* __restrict__ rowptr, int* __restrict__ cursor)
{
    const int i    = blockIdx.x * 256 + threadIdx.x;
    const int lane = threadIdx.x & 63;
    const int wid  = threadIdx.x >> 6;
    int v = (i < N_NODES) ? deg[i] : 0;
    int inc = v;
    #pragma unroll
    for (int off = 1; off < 64; off <<= 1) {
        int u = __shfl_up(inc, off);
        if (lane >= off) inc += u;
    }
    __shared__ int ws[4];
    if (lane == 63) ws[wid] = inc;
    __syncthreads();
    int add = boff[blockIdx.x];
    for (int w = 0; w < wid; ++w) add += ws[w];
    if (i < N_NODES) {
        const int ex = add + inc - v;
        rowptr[i] = ex;
        cursor[i] = ex;
    }
}

__global__ __launch_bounds__(256) void scatter_kernel(
    const int* __restrict__ eidx, int* __restrict__ cursor,
    unsigned short* __restrict__ csr_src)
{
    const int base = (blockIdx.x * 256 + threadIdx.x) * 8;
    if (base < N_EDGES) {
        const int4 s0 = *(const int4*)(eidx + base);
        const int4 s1 = *(const int4*)(eidx + base + 4);
        const int4 d0 = *(const int4*)(eidx + N_EDGES + base);
        const int4 d1 = *(const int4*)(eidx + N_EDGES + base + 4);
        const int t0 = atomicAdd(&cursor[d0.x], 1);
        const int t1 = atomicAdd(&cursor[d0.y], 1);
        const int t2 = atomicAdd(&cursor[d0.z], 1);
        const int t3 = atomicAdd(&cursor[d0.w], 1);
        const int t4 = atomicAdd(&cursor[d1.x], 1);
        const int t5 = atomicAdd(&cursor[d1.y], 1);
        const int t6 = atomicAdd(&cursor[d1.z], 1);
        const int t7 = atomicAdd(&cursor[d1.w], 1);
        csr_src[t0] = (unsigned short)s0.x;
        csr_src[t1] = (unsigned short)s0.y;
        csr_src[t2] = (unsigned short)s0.z;
        csr_src[t3] = (unsigned short)s0.w;
        csr_src[t4] = (unsigned short)s1.x;
        csr_src[t5] = (unsigned short)s1.y;
        csr_src[t6] = (unsigned short)s1.z;
        csr_src[t7] = (unsigned short)s1.w;
    } else if (base < ETOT) {
        const int d0 = base - N_EDGES;
        #pragma unroll
        for (int k = 0; k < 8; ++k) {
            const int t = atomicAdd(&cursor[d0 + k], 1);
            csr_src[t] = (unsigned short)(d0 + k);
        }
    }
}

// ====== fused per-node GAT (R13 form, unchanged): 16 lanes/edge, bf16 out ======
__global__ __launch_bounds__(256) void gat_node_kernel(
    const int* __restrict__ rowptr, const int* __restrict__ deg,
    const unsigned short* __restrict__ csr_src,
    const unsigned short* __restrict__ xlb, const unsigned short* __restrict__ xrb,
    const float* __restrict__ att, const float* __restrict__ bias,
    const float* __restrict__ gam, const float* __restrict__ bet,
    unsigned short* __restrict__ out)
{
    const int n    = blockIdx.x * 4 + (threadIdx.x >> 6);
    const int lane = threadIdx.x & 63;
    if (n >= N_NODES) return;
    const int q  = lane >> 4;       // edge slot 0..3
    const int r  = lane & 15;       // channel group
    const int c0 = r * 8;

    const ushort8v ur = *(const ushort8v*)(xrb + ((size_t)n << 7) + c0);
    float xrv[8];
    #pragma unroll
    for (int j = 0; j < 8; ++j) xrv[j] = bf2f(ur[j]);

    float a6[8], a4[8];
    #pragma unroll
    for (int j = 0; j < 8; ++j) {
        const float a = att[c0 + j];
        a6[j] = a * (0.6f * LOG2E);
        a4[j] = a * (0.4f * LOG2E);
    }

    float dsum = 0.f;
    float p[8];
    #pragma unroll
    for (int j = 0; j < 8; ++j) p[j] = 0.f;

    const int beg = rowptr[n];
    const int end = beg + deg[n];

    int e = beg;
    bool vcur = (e + q) < end;
    int s = vcur ? (int)csr_src[e + q] : 0;
    ushort8v u = *(const ushort8v*)(xlb + ((size_t)s << 7) + c0);

    while (e < end) {
        const int en = e + 4;
        ushort8v unext = u;
        bool vnext = false;
        if (en < end) {   // wave-uniform
            vnext = (en + q) < end;
            const int sn = vnext ? (int)csr_src[en + q] : 0;
            unext = *(const ushort8v*)(xlb + ((size_t)sn << 7) + c0);
        }
        float x[8];
        #pragma unroll
        for (int j = 0; j < 8; ++j) x[j] = bf2f(u[j]);
        float l = 0.f;
        #pragma unroll
        for (int j = 0; j < 8; ++j) {
            const float t = x[j] + xrv[j];
            l = fmaf(a6[j], t, fmaf(a4[j], fabsf(t), l));
        }
        l += __shfl_xor(l, 1);
        l += __shfl_xor(l, 2);
        l = vcur ? l : -INFINITY;
        const float w = exp2f(l);
        dsum += w;
        #pragma unroll
        for (int j = 0; j < 8; ++j) p[j] = fmaf(x[j], w, p[j]);

        u = unext; vcur = vnext; e = en;
    }

    dsum += __shfl_xor(dsum, 16);
    dsum += __shfl_xor(dsum, 32);
    #pragma unroll
    for (int j = 0; j < 8; ++j) {
        p[j] += __shfl_xor(p[j], 16);
        p[j] += __shfl_xor(p[j], 32);
    }

    const float inv = 1.f / dsum;
    float v[8];
    float s2 = 0.f, sq = 0.f;
    #pragma unroll
    for (int j = 0; j < 8; ++j) {
        v[j] = p[j] * inv + bias[c0 + j];
        s2 += v[j];
        sq  = fmaf(v[j], v[j], sq);
    }
    #pragma unroll
    for (int off = 1; off < 16; off <<= 1) {
        s2 += __shfl_xor(s2, off);
        sq += __shfl_xor(sq, off);
    }
    const float mu   = s2 * (1.f / 128.f);
    const float var  = sq * (1.f / 128.f) - mu * mu;
    const float rstd = rsqrtf(var + LN_EPS);

    if (q == 0) {
        float y[8];
        #pragma unroll
        for (int j = 0; j < 8; ++j)
            y[j] = gelu_exact((v[j] - mu) * rstd * gam[c0 + j] + bet[c0 + j]);
        uint4v o;
        o[0] = pk_bf16(y[0], y[1]);
        o[1] = pk_bf16(y[2], y[3]);
        o[2] = pk_bf16(y[4], y[5]);
        o[3] = pk_bf16(y[6], y[7]);
        *(uint4v*)(out + ((size_t)n << 7) + c0) = o;
    }
}

extern "C" void kernel_launch(void* const* d_in, const int* in_sizes, int n_in,
                              void* d_out, int out_size, void* d_ws, size_t ws_size,
                              hipStream_t stream)
{
    const float* x    = (const float*)d_in[0];
    const int*   eidx = (const int*)  d_in[1];

    const float* Wl[2]   = { (const float*)d_in[2],  (const float*)d_in[10] };
    const float* bl[2]   = { (const float*)d_in[3],  (const float*)d_in[11] };
    const float* Wr[2]   = { (const float*)d_in[4],  (const float*)d_in[12] };
    const float* br[2]   = { (const float*)d_in[5],  (const float*)d_in[13] };
    const float* att[2]  = { (const float*)d_in[6],  (const float*)d_in[14] };
    const float* bias[2] = { (const float*)d_in[7],  (const float*)d_in[15] };
    const float* gam[2]  = { (const float*)d_in[8],  (const float*)d_in[16] };
    const float* bet[2]  = { (const float*)d_in[9],  (const float*)d_in[17] };
    const float* Wout    = (const float*)d_in[18];
    const float* bout    = (const float*)d_in[19];
    const float* gout    = (const float*)d_in[20];
    const float* boutln  = (const float*)d_in[21];

    float* out = (float*)d_out;

    const size_t NF = (size_t)N_NODES * DH;
    unsigned short* xb  = (unsigned short*)d_ws;       // NF bf16 (x converted)
    unsigned short* xlb = xb + NF;                     // NF bf16 (gather operand)
    unsigned short* xrb = xlb + NF;                    // NF bf16
    unsigned short* hb  = xrb + NF;                    // NF bf16 (hidden act)
    unsigned short* csr_src = hb + NF;                 // ETOT u16
    int*   deg     = (int*)(csr_src + ETOT + 16);
    int*   rowptr  = deg + N_NODES;
    int*   cursor  = rowptr + N_NODES;
    int*   bsum    = cursor + N_NODES;
    int*   boff    = bsum + NBLK;
    short* whi     = (short*)(boff + NBLK);   // 5 * 16384 shorts
    short* wlo     = whi + 5 * 16384;

    const int csrBlocks  = (ETOT / 8 + 255) / 256;        // 416
    const int nodeBlocks = N_NODES / 4;
    const int gemmBlocks = (N_NODES + GTILE - 1) / GTILE; // 782
    const int prepBlocks = 320 + (int)(NF / 2048);        // 320 + 3125

    #define WP(i) (whi + (i) * 16384), (wlo + (i) * 16384)

    // ---- prep (also zeros deg) ----
    prep_kernel<<<prepBlocks, 256, 0, stream>>>(Wl[0], Wr[0], Wl[1], Wr[1], Wout,
                                                whi, wlo, x, xb, deg);

    // ---- CSR (deterministic rebuild every call) ----
    degree_kernel       <<<csrBlocks, 256, 0, stream>>>(eidx, deg);
    block_sum_kernel    <<<NBLK, 256, 0, stream>>>(deg, bsum);
    scan_partials_kernel<<<1, 256, 0, stream>>>(bsum, boff);
    rowptr_kernel       <<<NBLK, 256, 0, stream>>>(deg, boff, rowptr, cursor);
    scatter_kernel      <<<csrBlocks, 256, 0, stream>>>(eidx, cursor, csr_src);

    // ---- layer 0 ----
    gemm2_kernel<<<dim3(gemmBlocks, 2), 256, 0, stream>>>(
        xb, N_NODES, WP(0), bl[0], xlb, WP(1), br[0], xrb);
    gat_node_kernel<<<nodeBlocks, 256, 0, stream>>>(rowptr, deg, csr_src, xlb, xrb,
                                                    att[0], bias[0], gam[0], bet[0], hb);
    // ---- layer 1 ----
    gemm2_kernel<<<dim3(gemmBlocks, 2), 256, 0, stream>>>(
        hb, N_NODES, WP(2), bl[1], xlb, WP(3), br[1], xrb);
    gat_node_kernel<<<nodeBlocks, 256, 0, stream>>>(rowptr, deg, csr_src, xlb, xrb,
                                                    att[1], bias[1], gam[1], bet[1], hb);

    // ---- output projection + fused final LayerNorm ----
    gemm1_ln_kernel<<<gemmBlocks, 256, 0, stream>>>(
        hb, N_NODES, WP(4), bout, gout, boutln, out);
}

// Round 16
// 271.657 us; speedup vs baseline: 1.0982x; 1.0005x over previous
//
#include <hip/hip_runtime.h>
#include <math.h>

#define N_NODES 50000
#define N_EDGES 800000
#define ETOT    (N_EDGES + N_NODES)
#define DH      128
#define NH      4
#define LN_EPS  1e-5f
#define NBLK    ((N_NODES + 255) / 256)   // 196 scan blocks
#define LOG2E   1.4426950408889634f

typedef __attribute__((ext_vector_type(8))) short short8;
typedef __attribute__((ext_vector_type(8))) unsigned short ushort8v;
typedef __attribute__((ext_vector_type(4))) float f32x4;
typedef __attribute__((ext_vector_type(4))) unsigned uint4v;

// ---------- fp32 -> bf16 (RNE) helpers ----------
__device__ __forceinline__ unsigned short f2bf(float f) {
    unsigned u = __float_as_uint(f);
    u += 0x7FFFu + ((u >> 16) & 1u);
    return (unsigned short)(u >> 16);
}
__device__ __forceinline__ float bf2f(unsigned short h) {
    return __uint_as_float(((unsigned)h) << 16);
}
__device__ __forceinline__ unsigned pk_bf16(float a, float b) {
    unsigned h;
    asm("v_cvt_pk_bf16_f32 %0, %1, %2" : "=v"(h) : "v"(a), "v"(b));
    return h;
}

// ---------- fast exact-GELU (A&S 7.1.26 erf, max err ~1.5e-7) ----------
__device__ __forceinline__ float gelu_exact(float x) {
    const float z  = x * 0.70710678118654752f;
    const float az = fabsf(z);
    const float tt = __builtin_amdgcn_rcpf(fmaf(0.3275911f, az, 1.f));
    float p = fmaf(1.061405429f, tt, -1.453152027f);
    p = fmaf(p, tt, 1.421413741f);
    p = fmaf(p, tt, -0.284496736f);
    p = fmaf(p, tt, 0.254829592f);
    p = p * tt;
    const float ez = exp2f(-(z * z) * LOG2E);
    float er = fmaf(-p, ez, 1.f);
    er = copysignf(er, z);
    return x * fmaf(0.5f, er, 0.5f);
}

// ========== prep: pack 5 W (hi/lo) + convert x to bf16 + degree count ==========
// blocks [0,320): W pack; [320, 3445): x convert; [3445, 3861): degree atomics
// (deg must be zeroed before this kernel — memset on stream)
__global__ __launch_bounds__(256) void prep_kernel(
    const float* __restrict__ W0, const float* __restrict__ W1,
    const float* __restrict__ W2, const float* __restrict__ W3,
    const float* __restrict__ W4,
    short* __restrict__ hi, short* __restrict__ lo,
    const float* __restrict__ X, unsigned short* __restrict__ Xb,
    const int* __restrict__ eidx, int* __restrict__ deg)
{
    const int b = blockIdx.x;
    if (b < 320) {
        const int idx = b * 256 + threadIdx.x;   // 0..81919
        const int mat = idx >> 14;
        const int rem = idx & 16383;
        const int t = rem >> 12, c = (rem >> 9) & 7, l = (rem >> 3) & 63, j = rem & 7;
        const int k = t * 32 + (l >> 4) * 8 + j;
        const int n = c * 16 + (l & 15);
        const float* W = (mat == 0) ? W0 : (mat == 1) ? W1 : (mat == 2) ? W2
                       : (mat == 3) ? W3 : W4;
        const float v = W[k * DH + n];
        const unsigned short h = f2bf(v);
        hi[idx] = (short)h;
        lo[idx] = (short)f2bf(v - bf2f(h));
    } else if (b < 3445) {
        const size_t i = ((size_t)(b - 320) * 256 + threadIdx.x) * 8;   // NF = 3125*2048
        const float4 f0 = *(const float4*)(X + i);
        const float4 f1 = *(const float4*)(X + i + 4);
        uint4v o;
        o[0] = pk_bf16(f0.x, f0.y);
        o[1] = pk_bf16(f0.z, f0.w);
        o[2] = pk_bf16(f1.x, f1.y);
        o[3] = pk_bf16(f1.z, f1.w);
        *(uint4v*)(Xb + i) = o;
    } else {
        const int base = ((b - 3445) * 256 + threadIdx.x) * 8;
        if (base < N_EDGES) {
            const int4 d0 = *(const int4*)(eidx + N_EDGES + base);
            const int4 d1 = *(const int4*)(eidx + N_EDGES + base + 4);
            atomicAdd(&deg[d0.x], 1);
            atomicAdd(&deg[d0.y], 1);
            atomicAdd(&deg[d0.z], 1);
            atomicAdd(&deg[d0.w], 1);
            atomicAdd(&deg[d1.x], 1);
            atomicAdd(&deg[d1.y], 1);
            atomicAdd(&deg[d1.z], 1);
            atomicAdd(&deg[d1.w], 1);
        } else if (base < ETOT) {
            const int d0 = base - N_EDGES;
            #pragma unroll
            for (int k = 0; k < 8; ++k) atomicAdd(&deg[d0 + k], 1);
        }
    }
}

// ========== fused dual GEMM, column-split: 16 rows/wave, both L and R ==========
#define GTILE 64
__global__ __launch_bounds__(256) void gemm2_kernel(
    const unsigned short* __restrict__ A, int m_rows,
    const short* __restrict__ WhiL, const short* __restrict__ WloL,
    const float* __restrict__ biasL, unsigned short* __restrict__ YL,
    const short* __restrict__ WhiR, const short* __restrict__ WloR,
    const float* __restrict__ biasR, unsigned short* __restrict__ YR)
{
    const int w    = threadIdx.x >> 6;
    const int lane = threadIdx.x & 63;
    const int rows0 = blockIdx.x * GTILE + w * 16;
    const int ch   = blockIdx.y;          // column half 0/1
    const int g  = lane >> 4;
    const int rl = lane & 15;

    f32x4 accL[4], accR[4];
    #pragma unroll
    for (int c = 0; c < 4; ++c) {
        accL[c] = (f32x4){0.f, 0.f, 0.f, 0.f};
        accR[c] = (f32x4){0.f, 0.f, 0.f, 0.f};
    }

    for (int t = 0; t < 4; ++t) {
        int arow = rows0 + rl;
        arow = (arow < m_rows) ? arow : (m_rows - 1);
        const short8 a = *(const short8*)(A + (size_t)arow * DH + t * 32 + g * 8);
        #pragma unroll
        for (int c = 0; c < 4; ++c) {
            const int cc = ch * 4 + c;
            const int fidx = ((t * 8 + cc) * 64 + lane) * 8;
            const short8 bhL = *(const short8*)(WhiL + fidx);
            const short8 blL = *(const short8*)(WloL + fidx);
            const short8 bhR = *(const short8*)(WhiR + fidx);
            const short8 blR = *(const short8*)(WloR + fidx);
            accL[c] = __builtin_amdgcn_mfma_f32_16x16x32_bf16(a, bhL, accL[c], 0, 0, 0);
            accL[c] = __builtin_amdgcn_mfma_f32_16x16x32_bf16(a, blL, accL[c], 0, 0, 0);
            accR[c] = __builtin_amdgcn_mfma_f32_16x16x32_bf16(a, bhR, accR[c], 0, 0, 0);
            accR[c] = __builtin_amdgcn_mfma_f32_16x16x32_bf16(a, blR, accR[c], 0, 0, 0);
        }
    }
    #pragma unroll
    for (int c = 0; c < 4; ++c) {
        const int col = (ch * 4 + c) * 16 + rl;
        const float bL = biasL[col];
        const float bR = biasR[col];
        #pragma unroll
        for (int q = 0; q < 4; ++q) {
            const int row = rows0 + g * 4 + q;
            if (row < m_rows) {
                YL[(size_t)row * DH + col] = f2bf(accL[c][q] + bL);
                YR[(size_t)row * DH + col] = f2bf(accR[c][q] + bR);
            }
        }
    }
}

// ========== gemm1 + fused final LayerNorm: 16 rows/wave ==========
__global__ __launch_bounds__(256) void gemm1_ln_kernel(
    const unsigned short* __restrict__ A, int m_rows,
    const short* __restrict__ Whi, const short* __restrict__ Wlo,
    const float* __restrict__ bias,
    const float* __restrict__ gam, const float* __restrict__ bet,
    float* __restrict__ out)
{
    const int w    = threadIdx.x >> 6;
    const int lane = threadIdx.x & 63;
    const int rows0 = blockIdx.x * GTILE + w * 16;
    const int g  = lane >> 4;
    const int rl = lane & 15;

    f32x4 acc[8];
    #pragma unroll
    for (int c = 0; c < 8; ++c)
        acc[c] = (f32x4){0.f, 0.f, 0.f, 0.f};

    for (int t = 0; t < 4; ++t) {
        int arow = rows0 + rl;
        arow = (arow < m_rows) ? arow : (m_rows - 1);
        const short8 a = *(const short8*)(A + (size_t)arow * DH + t * 32 + g * 8);
        #pragma unroll
        for (int c = 0; c < 8; ++c) {
            const int fidx = ((t * 8 + c) * 64 + lane) * 8;
            const short8 bh = *(const short8*)(Whi + fidx);
            const short8 bl = *(const short8*)(Wlo + fidx);
            acc[c] = __builtin_amdgcn_mfma_f32_16x16x32_bf16(a, bh, acc[c], 0, 0, 0);
            acc[c] = __builtin_amdgcn_mfma_f32_16x16x32_bf16(a, bl, acc[c], 0, 0, 0);
        }
    }

    float bb[8], gg[8], bt8[8];
    #pragma unroll
    for (int c = 0; c < 8; ++c) {
        const int col = c * 16 + rl;
        bb[c] = bias[col];  gg[c] = gam[col];  bt8[c] = bet[col];
    }
    #pragma unroll
    for (int q = 0; q < 4; ++q) {
        float v[8];
        float s = 0.f, sq = 0.f;
        #pragma unroll
        for (int c = 0; c < 8; ++c) {
            v[c] = acc[c][q] + bb[c];
            s  += v[c];
            sq  = fmaf(v[c], v[c], sq);
        }
        #pragma unroll
        for (int off = 1; off < 16; off <<= 1) {
            s  += __shfl_xor(s,  off);
            sq += __shfl_xor(sq, off);
        }
        const float mu   = s * (1.f / 128.f);
        const float var  = sq * (1.f / 128.f) - mu * mu;
        const float rstd = rsqrtf(var + LN_EPS);
        const int row = rows0 + g * 4 + q;
        if (row < m_rows) {
            #pragma unroll
            for (int c = 0; c < 8; ++c)
                out[(size_t)row * DH + c * 16 + rl] =
                    (v[c] - mu) * rstd * gg[c] + bt8[c];
        }
    }
}

// ========================= CSR: block sums =========================
__global__ __launch_bounds__(256) void block_sum_kernel(
    const int* __restrict__ deg, int* __restrict__ bsum)
{
    const int i    = blockIdx.x * 256 + threadIdx.x;
    const int lane = threadIdx.x & 63;
    const int wid  = threadIdx.x >> 6;
    int v = (i < N_NODES) ? deg[i] : 0;
    #pragma unroll
    for (int off = 32; off; off >>= 1) v += __shfl_xor(v, off);
    __shared__ int ws[4];
    if (lane == 0) ws[wid] = v;
    __syncthreads();
    if (threadIdx.x == 0) bsum[blockIdx.x] = ws[0] + ws[1] + ws[2] + ws[3];
}

// ===== rowptr with inline scan of block sums (each block reduces bsum[0..b)) =====
__global__ __launch_bounds__(256) void rowptr_kernel(
    const int* __restrict__ deg, const int* __restrict__ bsum,
    int* __restrict__ rowptr, int* __restrict__ cursor)
{
    const int b    = blockIdx.x;
    const int tid  = threadIdx.x;
    const int lane = tid & 63;
    const int wid  = tid >> 6;

    // inline exclusive scan over block sums: boff = sum(bsum[0..b))
    int bv = (tid < b) ? bsum[tid] : 0;   // NBLK=196 < 256
    #pragma unroll
    for (int off = 32; off; off >>= 1) bv += __shfl_xor(bv, off);
    __shared__ int ws2[4];
    __shared__ int boffs;
    if (lane == 0) ws2[wid] = bv;
    __syncthreads();
    if (tid == 0) boffs = ws2[0] + ws2[1] + ws2[2] + ws2[3];
    __syncthreads();
    const int boff = boffs;

    const int i = b * 256 + tid;
    int v = (i < N_NODES) ? deg[i] : 0;
    int inc = v;
    #pragma unroll
    for (int off = 1; off < 64; off <<= 1) {
        int u = __shfl_up(inc, off);
        if (lane >= off) inc += u;
    }
    __shared__ int ws[4];
    if (lane == 63) ws[wid] = inc;
    __syncthreads();
    int add = boff;
    for (int w = 0; w < wid; ++w) add += ws[w];
    if (i < N_NODES) {
        const int ex = add + inc - v;
        rowptr[i] = ex;
        cursor[i] = ex;
    }
}

__global__ __launch_bounds__(256) void scatter_kernel(
    const int* __restrict__ eidx, int* __restrict__ cursor,
    unsigned short* __restrict__ csr_src)
{
    const int base = (blockIdx.x * 256 + threadIdx.x) * 8;
    if (base < N_EDGES) {
        const int4 s0 = *(const int4*)(eidx + base);
        const int4 s1 = *(const int4*)(eidx + base + 4);
        const int4 d0 = *(const int4*)(eidx + N_EDGES + base);
        const int4 d1 = *(const int4*)(eidx + N_EDGES + base + 4);
        const int t0 = atomicAdd(&cursor[d0.x], 1);
        const int t1 = atomicAdd(&cursor[d0.y], 1);
        const int t2 = atomicAdd(&cursor[d0.z], 1);
        const int t3 = atomicAdd(&cursor[d0.w], 1);
        const int t4 = atomicAdd(&cursor[d1.x], 1);
        const int t5 = atomicAdd(&cursor[d1.y], 1);
        const int t6 = atomicAdd(&cursor[d1.z], 1);
        const int t7 = atomicAdd(&cursor[d1.w], 1);
        csr_src[t0] = (unsigned short)s0.x;
        csr_src[t1] = (unsigned short)s0.y;
        csr_src[t2] = (unsigned short)s0.z;
        csr_src[t3] = (unsigned short)s0.w;
        csr_src[t4] = (unsigned short)s1.x;
        csr_src[t5] = (unsigned short)s1.y;
        csr_src[t6] = (unsigned short)s1.z;
        csr_src[t7] = (unsigned short)s1.w;
    } else if (base < ETOT) {
        const int d0 = base - N_EDGES;
        #pragma unroll
        for (int k = 0; k < 8; ++k) {
            const int t = atomicAdd(&cursor[d0 + k], 1);
            csr_src[t] = (unsigned short)(d0 + k);
        }
    }
}

// ====== fused per-node GAT: 16 lanes/edge, quarter-distributed GELU epilogue ======
__global__ __launch_bounds__(256) void gat_node_kernel(
    const int* __restrict__ rowptr, const int* __restrict__ deg,
    const unsigned short* __restrict__ csr_src,
    const unsigned short* __restrict__ xlb, const unsigned short* __restrict__ xrb,
    const float* __restrict__ att, const float* __restrict__ bias,
    const float* __restrict__ gam, const float* __restrict__ bet,
    unsigned short* __restrict__ out)
{
    const int n    = blockIdx.x * 4 + (threadIdx.x >> 6);
    const int lane = threadIdx.x & 63;
    if (n >= N_NODES) return;
    const int q  = lane >> 4;       // edge slot 0..3
    const int r  = lane & 15;       // channel group
    const int c0 = r * 8;

    const ushort8v ur = *(const ushort8v*)(xrb + ((size_t)n << 7) + c0);
    float xrv[8];
    #pragma unroll
    for (int j = 0; j < 8; ++j) xrv[j] = bf2f(ur[j]);

    float a6[8], a4[8];
    #pragma unroll
    for (int j = 0; j < 8; ++j) {
        const float a = att[c0 + j];
        a6[j] = a * (0.6f * LOG2E);
        a4[j] = a * (0.4f * LOG2E);
    }

    float dsum = 0.f;
    float p[8];
    #pragma unroll
    for (int j = 0; j < 8; ++j) p[j] = 0.f;

    const int beg = rowptr[n];
    const int end = beg + deg[n];

    int e = beg;
    bool vcur = (e + q) < end;
    int s = vcur ? (int)csr_src[e + q] : 0;
    ushort8v u = *(const ushort8v*)(xlb + ((size_t)s << 7) + c0);

    while (e < end) {
        const int en = e + 4;
        ushort8v unext = u;
        bool vnext = false;
        if (en < end) {   // wave-uniform
            vnext = (en + q) < end;
            const int sn = vnext ? (int)csr_src[en + q] : 0;
            unext = *(const ushort8v*)(xlb + ((size_t)sn << 7) + c0);
        }
        float x[8];
        #pragma unroll
        for (int j = 0; j < 8; ++j) x[j] = bf2f(u[j]);
        float l = 0.f;
        #pragma unroll
        for (int j = 0; j < 8; ++j) {
            const float t = x[j] + xrv[j];
            l = fmaf(a6[j], t, fmaf(a4[j], fabsf(t), l));
        }
        l += __shfl_xor(l, 1);
        l += __shfl_xor(l, 2);
        l = vcur ? l : -INFINITY;
        const float w = exp2f(l);
        dsum += w;
        #pragma unroll
        for (int j = 0; j < 8; ++j) p[j] = fmaf(x[j], w, p[j]);

        u = unext; vcur = vnext; e = en;
    }

    dsum += __shfl_xor(dsum, 16);
    dsum += __shfl_xor(dsum, 32);
    #pragma unroll
    for (int j = 0; j < 8; ++j) {
        p[j] += __shfl_xor(p[j], 16);
        p[j] += __shfl_xor(p[j], 32);
    }

    const float inv = 1.f / dsum;
    float v[8];
    float s2 = 0.f, sq = 0.f;
    #pragma unroll
    for (int j = 0; j < 8; ++j) {
        v[j] = p[j] * inv + bias[c0 + j];
        s2 += v[j];
        sq  = fmaf(v[j], v[j], sq);
    }
    #pragma unroll
    for (int off = 1; off < 16; off <<= 1) {
        s2 += __shfl_xor(s2, off);
        sq += __shfl_xor(sq, off);
    }
    const float mu   = s2 * (1.f / 128.f);
    const float var  = sq * (1.f / 128.f) - mu * mu;
    const float rstd = rsqrtf(var + LN_EPS);

    // quarter q handles channels c0+2q, c0+2q+1 (quarters hold identical v/mu/rstd)
    const int j0 = q * 2;
    const float ya = gelu_exact((v[j0]     - mu) * rstd * gam[c0 + j0]     + bet[c0 + j0]);
    const float yb = gelu_exact((v[j0 + 1] - mu) * rstd * gam[c0 + j0 + 1] + bet[c0 + j0 + 1]);
    ((unsigned*)out)[(size_t)n * 64 + r * 4 + q] = pk_bf16(ya, yb);
}

extern "C" void kernel_launch(void* const* d_in, const int* in_sizes, int n_in,
                              void* d_out, int out_size, void* d_ws, size_t ws_size,
                              hipStream_t stream)
{
    const float* x    = (const float*)d_in[0];
    const int*   eidx = (const int*)  d_in[1];

    const float* Wl[2]   = { (const float*)d_in[2],  (const float*)d_in[10] };
    const float* bl[2]   = { (const float*)d_in[3],  (const float*)d_in[11] };
    const float* Wr[2]   = { (const float*)d_in[4],  (const float*)d_in[12] };
    const float* br[2]   = { (const float*)d_in[5],  (const float*)d_in[13] };
    const float* att[2]  = { (const float*)d_in[6],  (const float*)d_in[14] };
    const float* bias[2] = { (const float*)d_in[7],  (const float*)d_in[15] };
    const float* gam[2]  = { (const float*)d_in[8],  (const float*)d_in[16] };
    const float* bet[2]  = { (const float*)d_in[9],  (const float*)d_in[17] };
    const float* Wout    = (const float*)d_in[18];
    const float* bout    = (const float*)d_in[19];
    const float* gout    = (const float*)d_in[20];
    const float* boutln  = (const float*)d_in[21];

    float* out = (float*)d_out;

    const size_t NF = (size_t)N_NODES * DH;
    unsigned short* xb  = (unsigned short*)d_ws;       // NF bf16 (x converted)
    unsigned short* xlb = xb + NF;                     // NF bf16 (gather operand)
    unsigned short* xrb = xlb + NF;                    // NF bf16
    unsigned short* hb  = xrb + NF;                    // NF bf16 (hidden act)
    unsigned short* csr_src = hb + NF;                 // ETOT u16
    int*   deg     = (int*)(csr_src + ETOT + 16);
    int*   rowptr  = deg + N_NODES;
    int*   cursor  = rowptr + N_NODES;
    int*   bsum    = cursor + N_NODES;
    short* whi     = (short*)(bsum + NBLK);   // 5 * 16384 shorts
    short* wlo     = whi + 5 * 16384;

    const int csrBlocks  = (ETOT / 8 + 255) / 256;        // 416
    const int nodeBlocks = N_NODES / 4;
    const int gemmBlocks = (N_NODES + GTILE - 1) / GTILE; // 782
    const int prepBlocks = 320 + (int)(NF / 2048) + csrBlocks;  // 320+3125+416

    #define WP(i) (whi + (i) * 16384), (wlo + (i) * 16384)

    // ---- zero deg, then prep (W pack + x convert + degree) ----
    hipMemsetAsync(deg, 0, N_NODES * sizeof(int), stream);
    prep_kernel<<<prepBlocks, 256, 0, stream>>>(Wl[0], Wr[0], Wl[1], Wr[1], Wout,
                                                whi, wlo, x, xb, eidx, deg);

    // ---- CSR ----
    block_sum_kernel<<<NBLK, 256, 0, stream>>>(deg, bsum);
    rowptr_kernel   <<<NBLK, 256, 0, stream>>>(deg, bsum, rowptr, cursor);
    scatter_kernel  <<<csrBlocks, 256, 0, stream>>>(eidx, cursor, csr_src);

    // ---- layer 0 ----
    gemm2_kernel<<<dim3(gemmBlocks, 2), 256, 0, stream>>>(
        xb, N_NODES, WP(0), bl[0], xlb, WP(1), br[0], xrb);
    gat_node_kernel<<<nodeBlocks, 256, 0, stream>>>(rowptr, deg, csr_src, xlb, xrb,
                                                    att[0], bias[0], gam[0], bet[0], hb);
    // ---- layer 1 ----
    gemm2_kernel<<<dim3(gemmBlocks, 2), 256, 0, stream>>>(
        hb, N_NODES, WP(2), bl[1], xlb, WP(3), br[1], xrb);
    gat_node_kernel<<<nodeBlocks, 256, 0, stream>>>(rowptr, deg, csr_src, xlb, xrb,
                                                    att[1], bias[1], gam[1], bet[1], hb);

    // ---- output projection + fused final LayerNorm ----
    gemm1_ln_kernel<<<gemmBlocks, 256, 0, stream>>>(
        hb, N_NODES, WP(4), bout, gout, boutln, out);
}